// Round 1
// baseline (331.496 us; speedup 1.0000x reference)
//
#include <hip/hip_runtime.h>

// Problem constants
#define BB 4
#define SS 2048
#define DD 512
#define HH 8
#define DKK 64
#define HDK 512   // H*DK

typedef __attribute__((ext_vector_type(4))) float f32x4;
typedef __attribute__((ext_vector_type(8))) __bf16 bf16x8;
typedef __attribute__((ext_vector_type(4))) __bf16 bf16x4;

#define MFMA16(a, b, c) __builtin_amdgcn_mfma_f32_16x16x32_bf16((a), (b), (c), 0, 0, 0)

// ---------------------------------------------------------------------------
// Kernel 1: fused convert + projection GEMM.
//   xh[m, he] = sum_d X[m,d] * Wq[he,d] + bq[he]
//   z=0 -> qh [B,H,S,DK], z=1 -> kh [B,H,S,DK], z=2 -> vt [B,H,DK,S] (transposed)
// Tile 64x64, BK=64, 4 waves (2x2), per-wave 2x2 fragments of 16x16.
// ---------------------------------------------------------------------------
__global__ __launch_bounds__(256) void proj_kernel(
    const float* __restrict__ q, const float* __restrict__ k, const float* __restrict__ v,
    const float* __restrict__ Wq, const float* __restrict__ bq,
    __bf16* __restrict__ qh, __bf16* __restrict__ kh, __bf16* __restrict__ vt)
{
    const int z  = blockIdx.z;
    const float* X = (z == 0) ? q : (z == 1) ? k : v;
    const int m0 = blockIdx.x * 64;
    const int n0 = blockIdx.y * 64;

    __shared__ __bf16 As[64][72];   // +8 pad: fragment reads <=2-way bank aliasing (free)
    __shared__ __bf16 Bs[64][72];

    const int t    = threadIdx.x;
    const int lane = t & 63, wid = t >> 6;
    const int lo   = lane & 15, hi = lane >> 4;
    const int wm   = wid >> 1, wn = wid & 1;

    f32x4 acc[2][2] = {};

    for (int k0 = 0; k0 < DD; k0 += 64) {
        __syncthreads();   // protect LDS against previous iteration's reads
        {
            const int row = t >> 4;          // 0..15
            const int col = (t & 15) * 4;    // 0..60
#pragma unroll
            for (int i = 0; i < 4; ++i) {
                const int r = row + i * 16;
                float4 a = *reinterpret_cast<const float4*>(&X[(size_t)(m0 + r) * DD + k0 + col]);
                bf16x4 ta = {(__bf16)a.x, (__bf16)a.y, (__bf16)a.z, (__bf16)a.w};
                *reinterpret_cast<bf16x4*>(&As[r][col]) = ta;
                float4 b = *reinterpret_cast<const float4*>(&Wq[(size_t)(n0 + r) * DD + k0 + col]);
                bf16x4 tb = {(__bf16)b.x, (__bf16)b.y, (__bf16)b.z, (__bf16)b.w};
                *reinterpret_cast<bf16x4*>(&Bs[r][col]) = tb;
            }
        }
        __syncthreads();
#pragma unroll
        for (int kk = 0; kk < 2; ++kk) {
            bf16x8 a[2], b[2];
#pragma unroll
            for (int mi = 0; mi < 2; ++mi)
                a[mi] = *reinterpret_cast<const bf16x8*>(&As[wm * 32 + mi * 16 + lo][kk * 32 + hi * 8]);
#pragma unroll
            for (int ni = 0; ni < 2; ++ni)
                b[ni] = *reinterpret_cast<const bf16x8*>(&Bs[wn * 32 + ni * 16 + lo][kk * 32 + hi * 8]);
#pragma unroll
            for (int mi = 0; mi < 2; ++mi)
#pragma unroll
                for (int ni = 0; ni < 2; ++ni)
                    acc[mi][ni] = MFMA16(a[mi], b[ni], acc[mi][ni]);
        }
    }

    // Epilogue: C/D layout col=lane&15, row=4*(lane>>4)+reg (m89-verified)
#pragma unroll
    for (int mi = 0; mi < 2; ++mi) {
#pragma unroll
        for (int ni = 0; ni < 2; ++ni) {
            const int n = n0 + wn * 32 + ni * 16 + lo;
            const float bias = bq[n];
            const int h_ = n >> 6, e_ = n & 63;
#pragma unroll
            for (int r = 0; r < 4; ++r) {
                const int m = m0 + wm * 32 + mi * 16 + hi * 4 + r;
                const float val = acc[mi][ni][r] + bias;
                const int b_ = m >> 11, s_ = m & (SS - 1);
                const size_t bh = (size_t)(b_ * HH + h_);
                if (z == 0)
                    qh[(bh * SS + s_) * DKK + e_] = (__bf16)val;
                else if (z == 1)
                    kh[(bh * SS + s_) * DKK + e_] = (__bf16)val;
                else
                    vt[(bh * DKK + e_) * SS + s_] = (__bf16)val;
            }
        }
    }
}

// ---------------------------------------------------------------------------
// Kernel 2: flash attention. Block = 64 q-rows (4 waves x 16 rows), KV tile = 32.
// scores D-tile: col(lane&15)=kv-within-chunk, row=4*(lane>>4)+r = q-row.
// Online softmax: row reductions over lane&15 via shfl_xor {1,2,4,8}.
// P re-layout D->A fragment via per-wave padded LDS buffer.
// ---------------------------------------------------------------------------
__global__ __launch_bounds__(256) void attn_kernel(
    const __bf16* __restrict__ qh, const __bf16* __restrict__ kh,
    const __bf16* __restrict__ vt, __bf16* __restrict__ concat)
{
    const int q0 = blockIdx.x * 64;
    const int bh = blockIdx.y;                // b*H + h
    const int b_ = bh >> 3, h_ = bh & 7;
    const size_t base = (size_t)bh * SS * DKK;
    const __bf16* qhp = qh + base;
    const __bf16* khp = kh + base;
    const __bf16* vtp = vt + base;            // [DK][S] per (b,h)

    const int t    = threadIdx.x;
    const int lane = t & 63, wid = t >> 6;
    const int lo   = lane & 15, hi = lane >> 4;

    __shared__ __bf16 Ks[32][72];        // K tile [kv][d], padded
    __shared__ __bf16 Vts[64][40];       // V^T tile [e][kv], padded
    __shared__ __bf16 Ps[4][16][40];     // per-wave P [q][kv], padded

    // Q fragments held in registers for the whole KV loop
    bf16x8 qf[2];
    {
        const int row = q0 + wid * 16 + lo;
        qf[0] = *reinterpret_cast<const bf16x8*>(&qhp[(size_t)row * DKK + hi * 8]);
        qf[1] = *reinterpret_cast<const bf16x8*>(&qhp[(size_t)row * DKK + 32 + hi * 8]);
    }

    f32x4 acc_o[4] = {};
    float m_run[4], l_run[4];
#pragma unroll
    for (int r = 0; r < 4; ++r) { m_run[r] = -INFINITY; l_run[r] = 0.f; }

    for (int kv0 = 0; kv0 < SS; kv0 += 32) {
        __syncthreads();  // previous PV LDS reads done before restage
        {
            const int krow = t >> 3, kcol = (t & 7) * 8;
            *reinterpret_cast<bf16x8*>(&Ks[krow][kcol]) =
                *reinterpret_cast<const bf16x8*>(&khp[(size_t)(kv0 + krow) * DKK + kcol]);
            const int vrow = t >> 2, vcol = (t & 3) * 8;
            *reinterpret_cast<bf16x8*>(&Vts[vrow][vcol]) =
                *reinterpret_cast<const bf16x8*>(&vtp[(size_t)vrow * SS + kv0 + vcol]);
        }
        __syncthreads();

        // scores: 16 q-rows x 32 kv
        f32x4 sc[2] = {};
#pragma unroll
        for (int kk = 0; kk < 2; ++kk) {
            bf16x8 b0 = *reinterpret_cast<const bf16x8*>(&Ks[lo][kk * 32 + hi * 8]);
            bf16x8 b1 = *reinterpret_cast<const bf16x8*>(&Ks[16 + lo][kk * 32 + hi * 8]);
            sc[0] = MFMA16(qf[kk], b0, sc[0]);
            sc[1] = MFMA16(qf[kk], b1, sc[1]);
        }

        // online softmax update (4 q-rows per lane)
#pragma unroll
        for (int r = 0; r < 4; ++r) {
            const float s0 = sc[0][r] * 0.125f;
            const float s1 = sc[1][r] * 0.125f;
            float mx = fmaxf(s0, s1);
#pragma unroll
            for (int msk = 1; msk < 16; msk <<= 1)
                mx = fmaxf(mx, __shfl_xor(mx, msk));
            const float mnew = fmaxf(m_run[r], mx);
            const float e0 = __expf(s0 - mnew);
            const float e1 = __expf(s1 - mnew);
            float rs = e0 + e1;
#pragma unroll
            for (int msk = 1; msk < 16; msk <<= 1)
                rs += __shfl_xor(rs, msk);
            const float scl = __expf(m_run[r] - mnew);
            l_run[r] = l_run[r] * scl + rs;
            m_run[r] = mnew;
#pragma unroll
            for (int nf = 0; nf < 4; ++nf)
                acc_o[nf][r] *= scl;
            Ps[wid][hi * 4 + r][lo]      = (__bf16)e0;
            Ps[wid][hi * 4 + r][16 + lo] = (__bf16)e1;
        }
        __syncthreads();  // P visible to the whole wave (cross-lane)

        // PV: heads += P[16x32] * V[32x64]
        bf16x8 pa = *reinterpret_cast<const bf16x8*>(&Ps[wid][lo][hi * 8]);
#pragma unroll
        for (int nf = 0; nf < 4; ++nf) {
            bf16x8 vb = *reinterpret_cast<const bf16x8*>(&Vts[nf * 16 + lo][hi * 8]);
            acc_o[nf] = MFMA16(pa, vb, acc_o[nf]);
        }
    }

    // epilogue: O = acc / l, write concat [B,S,H*DK] as bf16
#pragma unroll
    for (int r = 0; r < 4; ++r) {
        const float inv = 1.0f / l_run[r];
        const int qrow = q0 + wid * 16 + hi * 4 + r;
        const size_t obase = ((size_t)b_ * SS + qrow) * HDK + h_ * DKK;
#pragma unroll
        for (int nf = 0; nf < 4; ++nf)
            concat[obase + nf * 16 + lo] = (__bf16)(acc_o[nf][r] * inv);
    }
}

// ---------------------------------------------------------------------------
// Kernel 3: output projection. out[m,d] = sum_j concat[m,j]*Wout[d,j] + bout[d]
// ---------------------------------------------------------------------------
__global__ __launch_bounds__(256) void outproj_kernel(
    const __bf16* __restrict__ concat, const float* __restrict__ Wout,
    const float* __restrict__ bout, float* __restrict__ out)
{
    const int m0 = blockIdx.x * 64;
    const int n0 = blockIdx.y * 64;

    __shared__ __bf16 As[64][72];
    __shared__ __bf16 Bs[64][72];

    const int t    = threadIdx.x;
    const int lane = t & 63, wid = t >> 6;
    const int lo   = lane & 15, hi = lane >> 4;
    const int wm   = wid >> 1, wn = wid & 1;

    f32x4 acc[2][2] = {};

    for (int k0 = 0; k0 < HDK; k0 += 64) {
        __syncthreads();
        {
            // A: already bf16
            const int arow = t >> 3, acol = (t & 7) * 8;
#pragma unroll
            for (int i = 0; i < 2; ++i) {
                const int r = arow + i * 32;
                *reinterpret_cast<bf16x8*>(&As[r][acol]) =
                    *reinterpret_cast<const bf16x8*>(&concat[(size_t)(m0 + r) * HDK + k0 + acol]);
            }
            // B: fp32 Wout -> bf16
            const int row = t >> 4, col = (t & 15) * 4;
#pragma unroll
            for (int i = 0; i < 4; ++i) {
                const int r = row + i * 16;
                float4 b = *reinterpret_cast<const float4*>(&Wout[(size_t)(n0 + r) * HDK + k0 + col]);
                bf16x4 tb = {(__bf16)b.x, (__bf16)b.y, (__bf16)b.z, (__bf16)b.w};
                *reinterpret_cast<bf16x4*>(&Bs[r][col]) = tb;
            }
        }
        __syncthreads();
#pragma unroll
        for (int kk = 0; kk < 2; ++kk) {
            bf16x8 a[2], b[2];
#pragma unroll
            for (int mi = 0; mi < 2; ++mi)
                a[mi] = *reinterpret_cast<const bf16x8*>(&As[wm * 32 + mi * 16 + lo][kk * 32 + hi * 8]);
#pragma unroll
            for (int ni = 0; ni < 2; ++ni)
                b[ni] = *reinterpret_cast<const bf16x8*>(&Bs[wn * 32 + ni * 16 + lo][kk * 32 + hi * 8]);
#pragma unroll
            for (int mi = 0; mi < 2; ++mi)
#pragma unroll
                for (int ni = 0; ni < 2; ++ni)
                    acc[mi][ni] = MFMA16(a[mi], b[ni], acc[mi][ni]);
        }
    }

#pragma unroll
    for (int mi = 0; mi < 2; ++mi) {
#pragma unroll
        for (int ni = 0; ni < 2; ++ni) {
            const int n = n0 + wn * 32 + ni * 16 + lo;
            const float bias = bout[n];
#pragma unroll
            for (int r = 0; r < 4; ++r) {
                const int m = m0 + wm * 32 + mi * 16 + hi * 4 + r;
                out[(size_t)m * DD + n] = acc[mi][ni][r] + bias;
            }
        }
    }
}

// ---------------------------------------------------------------------------
extern "C" void kernel_launch(void* const* d_in, const int* in_sizes, int n_in,
                              void* d_out, int out_size, void* d_ws, size_t ws_size,
                              hipStream_t stream)
{
    (void)in_sizes; (void)n_in; (void)out_size; (void)ws_size;
    const float* q    = (const float*)d_in[0];
    const float* k    = (const float*)d_in[1];
    const float* v    = (const float*)d_in[2];
    const float* Wq   = (const float*)d_in[3];
    const float* bq   = (const float*)d_in[4];
    const float* Wout = (const float*)d_in[5];
    const float* bout = (const float*)d_in[6];
    float* out = (float*)d_out;

    char* ws = (char*)d_ws;
    __bf16* qh = (__bf16*)(ws);                      // 8 MiB  [B,H,S,DK]
    __bf16* kh = (__bf16*)(ws + (8u << 20));         // 8 MiB  [B,H,S,DK]
    __bf16* vt = (__bf16*)(ws + (16u << 20));        // 8 MiB  [B,H,DK,S]
    __bf16* cc = (__bf16*)(ws + (24u << 20));        // 8 MiB  [B,S,H*DK]

    proj_kernel<<<dim3(BB * SS / 64, HDK / 64, 3), 256, 0, stream>>>(q, k, v, Wq, bq, qh, kh, vt);
    attn_kernel<<<dim3(SS / 64, BB * HH), 256, 0, stream>>>(qh, kh, vt, cc);
    outproj_kernel<<<dim3(BB * SS / 64, DD / 64), 256, 0, stream>>>(cc, Wout, bout, out);
}

// Round 4
// 236.418 us; speedup vs baseline: 1.4022x; 1.4022x over previous
//
#include <hip/hip_runtime.h>

// Problem constants
#define BB 4
#define SS 2048
#define DD 512
#define HH 8
#define DKK 64
#define HDK 512   // H*DK

typedef __attribute__((ext_vector_type(4))) float f32x4;
typedef __attribute__((ext_vector_type(8))) __bf16 bf16x8;
typedef __attribute__((ext_vector_type(4))) __bf16 bf16x4;

#define MFMA16(a, b, c) __builtin_amdgcn_mfma_f32_16x16x32_bf16((a), (b), (c), 0, 0, 0)

// ---------------------------------------------------------------------------
// Kernel 1: fused convert + projection GEMM.  (unchanged from R1 — passed)
//   z=0 -> qh [B,H,S,DK], z=1 -> kh [B,H,S,DK], z=2 -> vt [B,H,DK,S]
// ---------------------------------------------------------------------------
__global__ __launch_bounds__(256) void proj_kernel(
    const float* __restrict__ q, const float* __restrict__ k, const float* __restrict__ v,
    const float* __restrict__ Wq, const float* __restrict__ bq,
    __bf16* __restrict__ qh, __bf16* __restrict__ kh, __bf16* __restrict__ vt)
{
    const int z  = blockIdx.z;
    const float* X = (z == 0) ? q : (z == 1) ? k : v;
    const int m0 = blockIdx.x * 64;
    const int n0 = blockIdx.y * 64;

    __shared__ __align__(16) __bf16 As[64][72];
    __shared__ __align__(16) __bf16 Bs[64][72];

    const int t    = threadIdx.x;
    const int lane = t & 63, wid = t >> 6;
    const int lo   = lane & 15, hi = lane >> 4;
    const int wm   = wid >> 1, wn = wid & 1;

    f32x4 acc[2][2] = {};

    for (int k0 = 0; k0 < DD; k0 += 64) {
        __syncthreads();
        {
            const int row = t >> 4;
            const int col = (t & 15) * 4;
#pragma unroll
            for (int i = 0; i < 4; ++i) {
                const int r = row + i * 16;
                float4 a = *reinterpret_cast<const float4*>(&X[(size_t)(m0 + r) * DD + k0 + col]);
                bf16x4 ta = {(__bf16)a.x, (__bf16)a.y, (__bf16)a.z, (__bf16)a.w};
                *reinterpret_cast<bf16x4*>(&As[r][col]) = ta;
                float4 b = *reinterpret_cast<const float4*>(&Wq[(size_t)(n0 + r) * DD + k0 + col]);
                bf16x4 tb = {(__bf16)b.x, (__bf16)b.y, (__bf16)b.z, (__bf16)b.w};
                *reinterpret_cast<bf16x4*>(&Bs[r][col]) = tb;
            }
        }
        __syncthreads();
#pragma unroll
        for (int kk = 0; kk < 2; ++kk) {
            bf16x8 a[2], b[2];
#pragma unroll
            for (int mi = 0; mi < 2; ++mi)
                a[mi] = *reinterpret_cast<const bf16x8*>(&As[wm * 32 + mi * 16 + lo][kk * 32 + hi * 8]);
#pragma unroll
            for (int ni = 0; ni < 2; ++ni)
                b[ni] = *reinterpret_cast<const bf16x8*>(&Bs[wn * 32 + ni * 16 + lo][kk * 32 + hi * 8]);
#pragma unroll
            for (int mi = 0; mi < 2; ++mi)
#pragma unroll
                for (int ni = 0; ni < 2; ++ni)
                    acc[mi][ni] = MFMA16(a[mi], b[ni], acc[mi][ni]);
        }
    }

#pragma unroll
    for (int mi = 0; mi < 2; ++mi) {
#pragma unroll
        for (int ni = 0; ni < 2; ++ni) {
            const int n = n0 + wn * 32 + ni * 16 + lo;
            const float bias = bq[n];
            const int h_ = n >> 6, e_ = n & 63;
#pragma unroll
            for (int r = 0; r < 4; ++r) {
                const int m = m0 + wm * 32 + mi * 16 + hi * 4 + r;
                const float val = acc[mi][ni][r] + bias;
                const int b_ = m >> 11, s_ = m & (SS - 1);
                const size_t bh = (size_t)(b_ * HH + h_);
                if (z == 0)
                    qh[(bh * SS + s_) * DKK + e_] = (__bf16)val;
                else if (z == 1)
                    kh[(bh * SS + s_) * DKK + e_] = (__bf16)val;
                else
                    vt[(bh * DKK + e_) * SS + s_] = (__bf16)val;
            }
        }
    }
}

// ---------------------------------------------------------------------------
// Kernel 2: flash attention, swapped-QK^T structure.
// Block = 128 q-rows, 4 waves x 32 q-rows (2 fragments of 16). KV tile = 64.
// Scores computed TRANSPOSED: S^T = mfma(K, Q) so lane (lo,hi) holds
// S^T[kv=16f+4hi+r][q=16g+lo] -> each lane owns 16 kv-slots of ONE q-row.
// Softmax: 15 in-reg fmax + 2 shfl_xor (16,32); exp in-reg; P staged to
// per-wave LDS (no block barrier needed) for the PV B-fragment relayout.
// PV also swapped: O^T = mfma(V^T, P^T); acc[f][g][r] = O[q=16g+lo][e=16f+4hi+r].
// K/V LDS tiles are [64][64] bf16, XOR-swizzled (byte ^= (row&7)<<4) on both
// the (reg-staged) write and the read — breaks the 32-way conflict.
// ---------------------------------------------------------------------------
__global__ __launch_bounds__(256) void attn_kernel(
    const __bf16* __restrict__ qh, const __bf16* __restrict__ kh,
    const __bf16* __restrict__ vt, __bf16* __restrict__ concat)
{
    const int q0 = blockIdx.x * 128;
    const int bh = blockIdx.y;                 // b*H + h
    const int b_ = bh >> 3, h_ = bh & 7;
    const size_t base = (size_t)bh * SS * DKK;
    const __bf16* qhp = qh + base;
    const __bf16* khp = kh + base;
    const __bf16* vtp = vt + base;             // [DK][S] per (b,h)

    const int t    = threadIdx.x;
    const int lane = t & 63, wid = t >> 6;
    const int lo   = lane & 15, hi = lane >> 4;

    __shared__ __align__(16) __bf16 Ks[64 * 64];    // swizzled [kv][d]
    __shared__ __align__(16) __bf16 Vts[64 * 64];   // swizzled [e][kv]
    __shared__ __align__(16) __bf16 Ps[4][32][72];  // per-wave P [q][kv], padded

    char* KsB  = (char*)Ks;
    char* VtsB = (char*)Vts;

    // staging geometry: wave w stages rows [16w,16w+16) of K and of V^T
    const int sr  = lane >> 3;                   // 0..7 row-within-chunk
    const int gcb = (lane & 7) << 4;             // linear col byte (global)
    const int scb = gcb ^ (sr << 4);             // swizzled col byte (LDS)
    const int srow = 16 * wid + sr;

    // Q fragments held in registers for the whole KV loop
    bf16x8 qf[2][2];
#pragma unroll
    for (int g = 0; g < 2; ++g)
#pragma unroll
        for (int kk = 0; kk < 2; ++kk)
            qf[g][kk] = *reinterpret_cast<const bf16x8*>(
                &qhp[(size_t)(q0 + 32 * wid + 16 * g + lo) * DKK + 32 * kk + 8 * hi]);

    f32x4 acc[4][2] = {};                        // [e-frag][q-frag]
    float m_run[2] = {-INFINITY, -INFINITY};
    float l_run[2] = {0.f, 0.f};

    for (int kv0 = 0; kv0 < SS; kv0 += 64) {
        // issue global loads before the barrier (latency overlap)
        bf16x8 kr0 = *reinterpret_cast<const bf16x8*>(
            (const char*)&khp[(size_t)(kv0 + srow) * DKK] + gcb);
        bf16x8 kr1 = *reinterpret_cast<const bf16x8*>(
            (const char*)&khp[(size_t)(kv0 + srow + 8) * DKK] + gcb);
        bf16x8 vr0 = *reinterpret_cast<const bf16x8*>(
            (const char*)&vtp[(size_t)srow * SS + kv0] + gcb);
        bf16x8 vr1 = *reinterpret_cast<const bf16x8*>(
            (const char*)&vtp[(size_t)(srow + 8) * SS + kv0] + gcb);

        __syncthreads();   // previous tile's LDS reads complete
        *reinterpret_cast<bf16x8*>(KsB  + srow * 128 + scb)       = kr0;
        *reinterpret_cast<bf16x8*>(KsB  + (srow + 8) * 128 + scb) = kr1;
        *reinterpret_cast<bf16x8*>(VtsB + srow * 128 + scb)       = vr0;
        *reinterpret_cast<bf16x8*>(VtsB + (srow + 8) * 128 + scb) = vr1;
        __syncthreads();   // tiles visible to all waves

        // ---- scores: S^T[kv 64][q 32] via mfma(K, Q) ----
        f32x4 sc[4][2] = {};
#pragma unroll
        for (int kk = 0; kk < 2; ++kk) {
            bf16x8 kf[4];
#pragma unroll
            for (int f = 0; f < 4; ++f) {
                const int row = 16 * f + lo;
                const int cb  = (64 * kk + 16 * hi) ^ ((row & 7) << 4);
                kf[f] = *reinterpret_cast<const bf16x8*>(KsB + row * 128 + cb);
            }
#pragma unroll
            for (int f = 0; f < 4; ++f)
#pragma unroll
                for (int g = 0; g < 2; ++g)
                    sc[f][g] = MFMA16(kf[f], qf[g][kk], sc[f][g]);
        }

        // ---- online softmax (per q-group; lane owns q = 16g+lo) ----
#pragma unroll
        for (int g = 0; g < 2; ++g) {
            float mx = -1e30f;
#pragma unroll
            for (int f = 0; f < 4; ++f)
#pragma unroll
                for (int r = 0; r < 4; ++r)
                    mx = fmaxf(mx, sc[f][g][r]);
            mx = fmaxf(mx, __shfl_xor(mx, 16));
            mx = fmaxf(mx, __shfl_xor(mx, 32));
            mx *= 0.125f;                         // scale after max (scale>0)
            const float mnew = fmaxf(m_run[g], mx);
            const float scl  = __expf(m_run[g] - mnew);
            float rs = 0.f;
#pragma unroll
            for (int f = 0; f < 4; ++f) {
                bf16x4 pk;
#pragma unroll
                for (int r = 0; r < 4; ++r) {
                    const float e = __expf(sc[f][g][r] * 0.125f - mnew);
                    rs += e;
                    pk[r] = (__bf16)e;
                }
                // P[q][kv]: kv = 16f+4hi+r contiguous over r
                *reinterpret_cast<bf16x4*>(&Ps[wid][16 * g + lo][16 * f + 4 * hi]) = pk;
            }
            rs += __shfl_xor(rs, 16);
            rs += __shfl_xor(rs, 32);
            l_run[g] = l_run[g] * scl + rs;
            m_run[g] = mnew;
#pragma unroll
            for (int f = 0; f < 4; ++f)
                acc[f][g] *= scl;
        }
        // NOTE: no __syncthreads here — Ps is per-wave; wave-internal
        // lgkmcnt ordering (compiler-inserted) suffices.

        // ---- PV: O^T += mfma(V^T, P^T) ----
#pragma unroll
        for (int kk = 0; kk < 2; ++kk) {
            bf16x8 pb[2];
#pragma unroll
            for (int g = 0; g < 2; ++g)
                pb[g] = *reinterpret_cast<const bf16x8*>(&Ps[wid][16 * g + lo][32 * kk + 8 * hi]);
#pragma unroll
            for (int f = 0; f < 4; ++f) {
                const int row = 16 * f + lo;                     // e index
                const int cb  = (64 * kk + 16 * hi) ^ ((row & 7) << 4);
                bf16x8 vf = *reinterpret_cast<const bf16x8*>(VtsB + row * 128 + cb);
#pragma unroll
                for (int g = 0; g < 2; ++g)
                    acc[f][g] = MFMA16(vf, pb[g], acc[f][g]);
            }
        }
    }

    // ---- epilogue: O[q][e] = acc/l, write concat [B,S,H*DK] ----
#pragma unroll
    for (int g = 0; g < 2; ++g) {
        const float inv = 1.0f / l_run[g];
        const int qrow = q0 + 32 * wid + 16 * g + lo;
        const size_t ob = ((size_t)b_ * SS + qrow) * HDK + h_ * DKK;
#pragma unroll
        for (int f = 0; f < 4; ++f) {
            bf16x4 o;
#pragma unroll
            for (int r = 0; r < 4; ++r)
                o[r] = (__bf16)(acc[f][g][r] * inv);
            *reinterpret_cast<bf16x4*>(&concat[ob + 16 * f + 4 * hi]) = o;
        }
    }
}

// ---------------------------------------------------------------------------
// Kernel 3: output projection.  (unchanged from R1 — passed)
// ---------------------------------------------------------------------------
__global__ __launch_bounds__(256) void outproj_kernel(
    const __bf16* __restrict__ concat, const float* __restrict__ Wout,
    const float* __restrict__ bout, float* __restrict__ out)
{
    const int m0 = blockIdx.x * 64;
    const int n0 = blockIdx.y * 64;

    __shared__ __align__(16) __bf16 As[64][72];
    __shared__ __align__(16) __bf16 Bs[64][72];

    const int t    = threadIdx.x;
    const int lane = t & 63, wid = t >> 6;
    const int lo   = lane & 15, hi = lane >> 4;
    const int wm   = wid >> 1, wn = wid & 1;

    f32x4 acc[2][2] = {};

    for (int k0 = 0; k0 < HDK; k0 += 64) {
        __syncthreads();
        {
            const int arow = t >> 3, acol = (t & 7) * 8;
#pragma unroll
            for (int i = 0; i < 2; ++i) {
                const int r = arow + i * 32;
                *reinterpret_cast<bf16x8*>(&As[r][acol]) =
                    *reinterpret_cast<const bf16x8*>(&concat[(size_t)(m0 + r) * HDK + k0 + acol]);
            }
            const int row = t >> 4, col = (t & 15) * 4;
#pragma unroll
            for (int i = 0; i < 4; ++i) {
                const int r = row + i * 16;
                float4 b = *reinterpret_cast<const float4*>(&Wout[(size_t)(n0 + r) * HDK + k0 + col]);
                bf16x4 tb = {(__bf16)b.x, (__bf16)b.y, (__bf16)b.z, (__bf16)b.w};
                *reinterpret_cast<bf16x4*>(&Bs[r][col]) = tb;
            }
        }
        __syncthreads();
#pragma unroll
        for (int kk = 0; kk < 2; ++kk) {
            bf16x8 a[2], b[2];
#pragma unroll
            for (int mi = 0; mi < 2; ++mi)
                a[mi] = *reinterpret_cast<const bf16x8*>(&As[wm * 32 + mi * 16 + lo][kk * 32 + hi * 8]);
#pragma unroll
            for (int ni = 0; ni < 2; ++ni)
                b[ni] = *reinterpret_cast<const bf16x8*>(&Bs[wn * 32 + ni * 16 + lo][kk * 32 + hi * 8]);
#pragma unroll
            for (int mi = 0; mi < 2; ++mi)
#pragma unroll
                for (int ni = 0; ni < 2; ++ni)
                    acc[mi][ni] = MFMA16(a[mi], b[ni], acc[mi][ni]);
        }
    }

#pragma unroll
    for (int mi = 0; mi < 2; ++mi) {
#pragma unroll
        for (int ni = 0; ni < 2; ++ni) {
            const int n = n0 + wn * 32 + ni * 16 + lo;
            const float bias = bout[n];
#pragma unroll
            for (int r = 0; r < 4; ++r) {
                const int m = m0 + wm * 32 + mi * 16 + hi * 4 + r;
                out[(size_t)m * DD + n] = acc[mi][ni][r] + bias;
            }
        }
    }
}

// ---------------------------------------------------------------------------
extern "C" void kernel_launch(void* const* d_in, const int* in_sizes, int n_in,
                              void* d_out, int out_size, void* d_ws, size_t ws_size,
                              hipStream_t stream)
{
    (void)in_sizes; (void)n_in; (void)out_size; (void)ws_size;
    const float* q    = (const float*)d_in[0];
    const float* k    = (const float*)d_in[1];
    const float* v    = (const float*)d_in[2];
    const float* Wq   = (const float*)d_in[3];
    const float* bq   = (const float*)d_in[4];
    const float* Wout = (const float*)d_in[5];
    const float* bout = (const float*)d_in[6];
    float* out = (float*)d_out;

    char* ws = (char*)d_ws;
    __bf16* qh = (__bf16*)(ws);                      // 8 MiB  [B,H,S,DK]
    __bf16* kh = (__bf16*)(ws + (8u << 20));         // 8 MiB  [B,H,S,DK]
    __bf16* vt = (__bf16*)(ws + (16u << 20));        // 8 MiB  [B,H,DK,S]
    __bf16* cc = (__bf16*)(ws + (24u << 20));        // 8 MiB  [B,S,H*DK]

    proj_kernel<<<dim3(BB * SS / 64, HDK / 64, 3), 256, 0, stream>>>(q, k, v, Wq, bq, qh, kh, vt);
    attn_kernel<<<dim3(SS / 128, BB * HH), 256, 0, stream>>>(qh, kh, vt, cc);
    outproj_kernel<<<dim3(BB * SS / 64, DD / 64), 256, 0, stream>>>(cc, Wout, bout, out);
}